// Round 1
// 542.111 us; speedup vs baseline: 1.1100x; 1.1100x over previous
//
#include <hip/hip_runtime.h>
#include <hip/hip_bf16.h>

typedef __hip_bfloat16 bf16;
typedef __attribute__((ext_vector_type(8))) short short8;   // 8 bf16 = 4 VGPRs
typedef __attribute__((ext_vector_type(4))) float f32x4;

__device__ __forceinline__ float b2f(bf16 x) { return __bfloat162float(x); }
__device__ __forceinline__ float bits2f(unsigned short u) {
    return __uint_as_float(((unsigned)u) << 16);
}

// ---------------- dtype probe (inputs proven fp32; kept as cheap insurance) ----------------
__global__ __launch_bounds__(64) void k_probe(const void* __restrict__ feat, int* __restrict__ mode) {
    const bf16* p = (const bf16*)feat;
    int lane = threadIdx.x;
    float m = 0.f;
    for (int i = lane; i < 2048; i += 64) {
        float v = fabsf(b2f(p[2 * i]));
        if (!(v < 1e30f)) v = 1e30f;
        m = fmaxf(m, v);
    }
    #pragma unroll
    for (int off = 32; off > 0; off >>= 1) m = fmaxf(m, __shfl_xor(m, off, 64));
    if (lane == 0) *mode = (m > 1e8f) ? 1 : 0;   // 1 = inputs are fp32
}

// all 20 weight tensors; grid (20, 8): x = tensor, y = chunk
struct StageDesc { const void* src; float* dst; int n; };
struct StageArgs { StageDesc d[20]; };
__global__ __launch_bounds__(256) void k_stage_all(StageArgs args, const int* __restrict__ mode) {
    const StageDesc sd = args.d[blockIdx.x];
    int m = *mode;
    for (int t = blockIdx.y * 256 + threadIdx.x; t < sd.n; t += 8 * 256) {
        float v = m ? ((const float*)sd.src)[t] : b2f(((const bf16*)sd.src)[t]);
        sd.dst[t] = v;
    }
}

// zero counts[N] and bn partial buffers (both layers)
__global__ __launch_bounds__(256) void k_zero_all(int* __restrict__ counts, float* __restrict__ bn0,
                                                  float* __restrict__ bn1, int n) {
    int t = blockIdx.x * 256 + threadIdx.x;
    if (t < n) counts[t] = 0;
    if (t < 256) { bn0[t] = 0.f; bn1[t] = 0.f; }
}

// ---------------- CSR build (by dst) ----------------

__global__ __launch_bounds__(256) void k_hist(const int* __restrict__ dst, int* __restrict__ counts, int e) {
    int t = blockIdx.x * 256 + threadIdx.x;
    if (t < e) atomicAdd(&counts[dst[t]], 1);
}

// block-strided scan, 4 elements/thread (int4): 13 serial rounds instead of 49
__global__ __launch_bounds__(1024) void k_scan(const int* __restrict__ counts, int* __restrict__ row_ptr,
                                               int* __restrict__ cursor, int n) {
    __shared__ int wsum[16];
    __shared__ int carry_s;
    int lane = threadIdx.x & 63, w = threadIdx.x >> 6;
    if (threadIdx.x == 0) carry_s = 0;
    __syncthreads();
    for (int base = 0; base < n; base += 4096) {
        int i0 = base + (int)threadIdx.x * 4;
        int4 v = {0, 0, 0, 0};
        if (i0 + 3 < n) v = *(const int4*)(counts + i0);
        else if (i0 < n) {
            v.x = counts[i0];
            if (i0 + 1 < n) v.y = counts[i0 + 1];
            if (i0 + 2 < n) v.z = counts[i0 + 2];
        }
        int t1 = v.x + v.y, t2 = t1 + v.z, t3 = t2 + v.w;   // in-thread inclusive
        int x = t3;
        #pragma unroll
        for (int off = 1; off < 64; off <<= 1) {
            int t = __shfl_up(x, off, 64);
            if (lane >= off) x += t;
        }
        if (lane == 63) wsum[w] = x;
        __syncthreads();
        if (w == 0 && lane < 16) {
            int s = wsum[lane];
            #pragma unroll
            for (int off = 1; off < 16; off <<= 1) {
                int t = __shfl_up(s, off, 64);
                if (lane >= off) s += t;
            }
            wsum[lane] = s;
        }
        __syncthreads();
        int carry = carry_s;
        int woff = (w == 0) ? 0 : wsum[w - 1];
        int e0 = carry + woff + x - t3;                      // exclusive prefix of elem i0
        if (i0 + 3 < n) {
            int4 rp = {e0, e0 + v.x, e0 + t1, e0 + t2};
            *(int4*)(row_ptr + i0) = rp;
            *(int4*)(cursor + i0) = rp;
        } else if (i0 < n) {
            row_ptr[i0] = e0; cursor[i0] = e0;
            if (i0 + 1 < n) { row_ptr[i0 + 1] = e0 + v.x; cursor[i0 + 1] = e0 + v.x; }
            if (i0 + 2 < n) { row_ptr[i0 + 2] = e0 + t1; cursor[i0 + 2] = e0 + t1; }
        }
        __syncthreads();
        if (threadIdx.x == 0) carry_s = carry + wsum[15];
        __syncthreads();
    }
    if (threadIdx.x == 0) row_ptr[n] = carry_s;
}

__global__ __launch_bounds__(256) void k_scatter(const int* __restrict__ src, const int* __restrict__ dst,
                                                 int* __restrict__ cursor, int* __restrict__ ssrc, int e) {
    int t = blockIdx.x * 256 + threadIdx.x;
    if (t < e) {
        int d = dst[t];
        int idx = atomicAdd(&cursor[d], 1);
        ssrc[idx] = src[t];
    }
}

// ---------------- all 3 layers' weight transpose+cast in one launch ----------------
__global__ __launch_bounds__(256) void k_wt_all(const float* __restrict__ Wc0, const float* __restrict__ Wl0,
                                                const float* __restrict__ Wc1, const float* __restrict__ Wl1,
                                                const float* __restrict__ Wc2, const float* __restrict__ Wl2,
                                                bf16* __restrict__ Wt0, bf16* __restrict__ Wt1,
                                                bf16* __restrict__ Wt2) {
    int t = blockIdx.x * 256 + threadIdx.x;
    const float* Wc; const float* Wl; bf16* Wt; int HC;
    if (t < 32768)       { Wc = Wc0; Wl = Wl0; Wt = Wt0; HC = 128; }
    else if (t < 65536)  { t -= 32768; Wc = Wc1; Wl = Wl1; Wt = Wt1; HC = 128; }
    else if (t < 106496) { t -= 65536; Wc = Wc2; Wl = Wl2; Wt = Wt2; HC = 160; }
    else return;
    int k = t & 127, c = t >> 7;
    float v = (c < HC) ? Wc[k * HC + c] : Wl[k * HC + c - HC];
    Wt[(size_t)c * 128 + k] = __float2bfloat16(v);
}

// ---------------- MFMA GEMM, col-fused: A read once (or twice for HC=160) ----------------
// AF32P: layer-0 variant that reads A directly from feat (fp32 or bf16 per *mode)
// FELR : fuse el/er computation into the epilogue (HC=128 layers; wave holds full 256-col rows)
template <int HC, int CT, bool AF32P, bool FELR>
__global__ __launch_bounds__(256) void k_gemm_mfma(const void* __restrict__ Av, const int* __restrict__ mode,
                                                   const bf16* __restrict__ Wt,
                                                   bf16* __restrict__ Zh, float* __restrict__ Lin,
                                                   const float* __restrict__ alp, const float* __restrict__ arp,
                                                   float* __restrict__ elp, float* __restrict__ erp, int n) {
    int tid = threadIdx.x;
    int wv = tid >> 6, lane = tid & 63;
    int quad = lane >> 4, m16 = lane & 15;
    int row0 = blockIdx.x * 64 + wv * 16;
    int col0 = blockIdx.y * (CT * 16);
    f32x4 acc[CT] = {};
    int arow = row0 + m16;
    if (arow >= n) arow = n - 1;
    bool af32 = false;
    if constexpr (AF32P) af32 = (*mode != 0);
    const short8* Arow = (const short8*)((const bf16*)Av + (size_t)arow * 128);
    const float4* Arow32 = (const float4*)((const float*)Av + (size_t)arow * 128);
    #pragma unroll
    for (int k8 = 0; k8 < 16; k8 += 4) {
        short8 a;
        if (AF32P && af32) {
            float4 f0 = Arow32[2 * (k8 + quad)];
            float4 f1 = Arow32[2 * (k8 + quad) + 1];
            union { bf16 h[8]; short8 s; } u;
            u.h[0] = __float2bfloat16(f0.x); u.h[1] = __float2bfloat16(f0.y);
            u.h[2] = __float2bfloat16(f0.z); u.h[3] = __float2bfloat16(f0.w);
            u.h[4] = __float2bfloat16(f1.x); u.h[5] = __float2bfloat16(f1.y);
            u.h[6] = __float2bfloat16(f1.z); u.h[7] = __float2bfloat16(f1.w);
            a = u.s;
        } else {
            a = Arow[k8 + quad];
        }
        #pragma unroll
        for (int c = 0; c < CT; c++) {
            const short8* Brow = (const short8*)(Wt + (size_t)(col0 + c * 16 + m16) * 128);
            short8 b = Brow[k8 + quad];
            acc[c] = __builtin_amdgcn_mfma_f32_16x16x32_bf16(a, b, acc[c], 0, 0, 0);
        }
    }
    if constexpr (FELR) {
        // el[r,h] = sum_d z[r,h*32+d]*al[h*32+d]; lane holds cols {c*16+m16}.
        // head h -> tiles 2h (d=m16) and 2h+1 (d=16+m16); reduce over the 16 m16-lanes.
        float a0[4], a1[4], r0[4], r1[4];
        #pragma unroll
        for (int h = 0; h < 4; h++) {
            a0[h] = alp[h * 32 + m16]; a1[h] = alp[h * 32 + 16 + m16];
            r0[h] = arp[h * 32 + m16]; r1[h] = arp[h * 32 + 16 + m16];
        }
        #pragma unroll
        for (int reg = 0; reg < 4; reg++) {
            float eh[8];
            #pragma unroll
            for (int h = 0; h < 4; h++) {
                eh[h]     = acc[2 * h][reg] * a0[h] + acc[2 * h + 1][reg] * a1[h];
                eh[4 + h] = acc[2 * h][reg] * r0[h] + acc[2 * h + 1][reg] * r1[h];
            }
            #pragma unroll
            for (int off = 1; off < 16; off <<= 1) {
                #pragma unroll
                for (int k = 0; k < 8; k++) eh[k] += __shfl_xor(eh[k], off, 64);
            }
            int r = row0 + quad * 4 + reg;
            // lane m16<4 writes head m16 (static-index via select chain; no scratch)
            float vl = (m16 & 2) ? ((m16 & 1) ? eh[3] : eh[2]) : ((m16 & 1) ? eh[1] : eh[0]);
            float vr = (m16 & 2) ? ((m16 & 1) ? eh[7] : eh[6]) : ((m16 & 1) ? eh[5] : eh[4]);
            if (r < n && m16 < 4) { elp[(size_t)r * 4 + m16] = vl; erp[(size_t)r * 4 + m16] = vr; }
        }
    }
    #pragma unroll
    for (int c = 0; c < CT; c++) {
        int gc = col0 + c * 16 + m16;
        #pragma unroll
        for (int reg = 0; reg < 4; reg++) {
            int r = row0 + quad * 4 + reg;
            if (r >= n) continue;
            float v = acc[c][reg];
            if (gc < HC) Zh[(size_t)r * HC + gc] = __float2bfloat16(v);
            else         Lin[(size_t)r * HC + gc - HC] = v;
        }
    }
}

// ---------------- el/er from bf16 Z (layer 2 only; layers 0/1 fused into GEMM) ----------------
template <int HC, int D>
__global__ __launch_bounds__(256) void k_elr(const bf16* __restrict__ Z, const float* __restrict__ al,
                                             const float* __restrict__ ar, float* __restrict__ el,
                                             float* __restrict__ er, int n) {
    int t = blockIdx.x * 256 + threadIdx.x;
    if (t >= n * 4) return;
    int node = t >> 2, h = t & 3;
    const __hip_bfloat162* zp = (const __hip_bfloat162*)(Z + (size_t)node * HC + h * D);
    const float* alp = al + h * D;
    const float* arp = ar + h * D;
    float sl = 0.f, sr = 0.f;
    #pragma unroll
    for (int d2 = 0; d2 < D / 2; d2++) {
        __hip_bfloat162 z = zp[d2];
        float zx = b2f(z.x), zy = b2f(z.y);
        sl += zx * alp[2 * d2] + zy * alp[2 * d2 + 1];
        sr += zx * arp[2 * d2] + zy * arp[2 * d2 + 1];
    }
    el[t] = sl;
    er[t] = sr;
}

// ---------------- fused edge softmax + gather, MLP-unrolled inner loop ----------------
// UN slots processed per iteration => UN independent Z-row loads in flight per wave.
template <int HC, int D, bool LAST>
__global__ __launch_bounds__(256, 8) void k_gather(const int* __restrict__ row_ptr, const int* __restrict__ ssrc,
                                                   const float* __restrict__ el, const float* __restrict__ er,
                                                   const float* __restrict__ bc, const bf16* __restrict__ Z,
                                                   float* __restrict__ Y, const float* __restrict__ bias,
                                                   float* __restrict__ out, int n) {
    constexpr int DPL = HC / 16;           // 8 (HC=128) or 10 (HC=160)
    constexpr int UN = (DPL == 8) ? 4 : 2; // unroll factor of the edge-slot loop
    int node = (int)((blockIdx.x * blockDim.x + threadIdx.x) >> 6);
    int lane = threadIdx.x & 63;
    if (node >= n) return;
    int qi = lane >> 4;
    int t16 = lane & 15;
    int hq = t16 >> 2;
    int beg = row_ptr[node], end = row_ptr[node + 1];
    float4 er4 = ((const float4*)er)[node];
    const float4* el4p = (const float4*)el;
    const bf16* Zt = Z + t16 * DPL;
    float acc[DPL];
    #pragma unroll
    for (int k = 0; k < DPL; k++) acc[k] = 0.f;
    float ss = 0.f;
    for (int base = beg; base < end; base += 64) {
        int idx = base + lane;
        bool valid = idx < end;
        int s_my = valid ? ssrc[idx] : 0;          // coalesced
        float4 e4 = el4p[s_my];                    // one random 16B per lane (L2-resident)
        float x0 = e4.x + er4.x; x0 = x0 > 0.f ? x0 : 0.2f * x0;
        float x1 = e4.y + er4.y; x1 = x1 > 0.f ? x1 : 0.2f * x1;
        float x2 = e4.z + er4.z; x2 = x2 > 0.f ? x2 : 0.2f * x2;
        float x3 = e4.w + er4.w; x3 = x3 > 0.f ? x3 : 0.2f * x3;
        float w0 = valid ? __expf(x0) : 0.f;
        float w1 = valid ? __expf(x1) : 0.f;
        float w2 = valid ? __expf(x2) : 0.f;
        float w3 = valid ? __expf(x3) : 0.f;
        int cnt = end - base; if (cnt > 64) cnt = 64;
        int iters = (cnt + 3) >> 2;                // wave-uniform trip count, 1..16
        for (int j = 0; j < iters; j += UN) {
            int sv[UN]; float gv[UN];
            #pragma unroll
            for (int f = 0; f < UN; f++) {
                int sl = qi + ((j + f) << 2);      // <= 63 always; w's are 0 past cnt
                sv[f] = __shfl(s_my, sl, 64);
                float a0 = __shfl(w0, sl, 64);
                float a1 = __shfl(w1, sl, 64);
                float a2 = __shfl(w2, sl, 64);
                float a3 = __shfl(w3, sl, 64);
                gv[f] = (hq & 2) ? ((hq & 1) ? a3 : a2) : ((hq & 1) ? a1 : a0);
                ss += gv[f];
            }
            if constexpr (DPL == 8) {
                short8 z[UN];
                #pragma unroll
                for (int f = 0; f < UN; f++) z[f] = *(const short8*)(Zt + (size_t)sv[f] * HC);
                #pragma unroll
                for (int f = 0; f < UN; f++) {
                    #pragma unroll
                    for (int k = 0; k < 8; k++)
                        acc[k] += gv[f] * bits2f((unsigned short)z[f][k]);
                }
            } else {
                __hip_bfloat162 z[UN][DPL / 2];
                #pragma unroll
                for (int f = 0; f < UN; f++) {
                    const __hip_bfloat162* z2 = (const __hip_bfloat162*)(Zt + (size_t)sv[f] * HC);
                    #pragma unroll
                    for (int k2 = 0; k2 < DPL / 2; k2++) z[f][k2] = z2[k2];
                }
                #pragma unroll
                for (int f = 0; f < UN; f++) {
                    #pragma unroll
                    for (int k2 = 0; k2 < DPL / 2; k2++) {
                        acc[2 * k2]     += gv[f] * b2f(z[f][k2].x);
                        acc[2 * k2 + 1] += gv[f] * b2f(z[f][k2].y);
                    }
                }
            }
        }
    }
    #pragma unroll
    for (int k = 0; k < DPL; k++) {
        acc[k] += __shfl_xor(acc[k], 16, 64);
        acc[k] += __shfl_xor(acc[k], 32, 64);
    }
    ss += __shfl_xor(ss, 16, 64);
    ss += __shfl_xor(ss, 32, 64);
    float inv = (end > beg) ? 1.f / ss : 0.f;
    if constexpr (!LAST) {
        if ((lane & 48) == 0) {
            float* yr = Y + (size_t)node * HC + t16 * DPL;
            const float* bcr = bc + t16 * DPL;
            #pragma unroll
            for (int k = 0; k < DPL; k++) yr[k] += acc[k] * inv + bcr[k];
        }
    } else {
        float yv[DPL];
        const float* lr = Y + (size_t)node * HC + t16 * DPL;   // Y = lin (read-only)
        const float* bcr = bc + t16 * DPL;
        #pragma unroll
        for (int k = 0; k < DPL; k++) yv[k] = acc[k] * inv + bcr[k] + lr[k];
        #pragma unroll
        for (int k = 0; k < DPL; k++) {
            yv[k] += __shfl_xor(yv[k], 4, 64);
            yv[k] += __shfl_xor(yv[k], 8, 64);
        }
        if (lane < 4) {
            float* orow = out + (size_t)node * 40 + t16 * DPL;
            const float* br = bias + t16 * DPL;
            #pragma unroll
            for (int k = 0; k < DPL; k++) orow[k] = 0.25f * yv[k] + br[k];
        }
    }
}

// ---------------- BatchNorm stats: 128 blocks (low atomic contention) + pipelined loads ----------------
__global__ __launch_bounds__(256) void k_bn_stats(const float* __restrict__ Y, float* __restrict__ sum,
                                                  float* __restrict__ sumsq, int n) {
    __shared__ float4 lds_s[8][32];
    __shared__ float4 lds_q[8][32];
    int t = threadIdx.x;
    int q = t & 31, g = t >> 5;
    const float4* Y4 = (const float4*)Y;
    float4 s = {0.f, 0.f, 0.f, 0.f}, ss = {0.f, 0.f, 0.f, 0.f};
    const int stride = 128 * 8;
    int r = blockIdx.x * 8 + g;
    for (; r + stride < n; r += 2 * stride) {
        float4 v0 = Y4[(size_t)r * 32 + q];
        float4 v1 = Y4[(size_t)(r + stride) * 32 + q];
        s.x += v0.x; s.y += v0.y; s.z += v0.z; s.w += v0.w;
        ss.x += v0.x * v0.x; ss.y += v0.y * v0.y; ss.z += v0.z * v0.z; ss.w += v0.w * v0.w;
        s.x += v1.x; s.y += v1.y; s.z += v1.z; s.w += v1.w;
        ss.x += v1.x * v1.x; ss.y += v1.y * v1.y; ss.z += v1.z * v1.z; ss.w += v1.w * v1.w;
    }
    if (r < n) {
        float4 v = Y4[(size_t)r * 32 + q];
        s.x += v.x; s.y += v.y; s.z += v.z; s.w += v.w;
        ss.x += v.x * v.x; ss.y += v.y * v.y; ss.z += v.z * v.z; ss.w += v.w * v.w;
    }
    lds_s[g][q] = s; lds_q[g][q] = ss;
    __syncthreads();
    if (t < 32) {
        float4 S = lds_s[0][t], Q = lds_q[0][t];
        #pragma unroll
        for (int g2 = 1; g2 < 8; g2++) {
            float4 a = lds_s[g2][t], b = lds_q[g2][t];
            S.x += a.x; S.y += a.y; S.z += a.z; S.w += a.w;
            Q.x += b.x; Q.y += b.y; Q.z += b.z; Q.w += b.w;
        }
        atomicAdd(&sum[4 * t + 0], S.x); atomicAdd(&sum[4 * t + 1], S.y);
        atomicAdd(&sum[4 * t + 2], S.z); atomicAdd(&sum[4 * t + 3], S.w);
        atomicAdd(&sumsq[4 * t + 0], Q.x); atomicAdd(&sumsq[4 * t + 1], Q.y);
        atomicAdd(&sumsq[4 * t + 2], Q.z); atomicAdd(&sumsq[4 * t + 3], Q.w);
    }
}

// BN + ReLU -> bf16, 4 channels/thread
__global__ __launch_bounds__(256) void k_bn_apply(const float* __restrict__ Y, const float* __restrict__ sum,
                                                  const float* __restrict__ sumsq, const float* __restrict__ g,
                                                  const float* __restrict__ b, bf16* __restrict__ out, int n) {
    int t = blockIdx.x * 256 + threadIdx.x;
    if (t >= n * 32) return;
    int c4 = (t & 31) * 4;
    float4 v = ((const float4*)Y)[t];
    float invn = 1.f / (float)n;
    union { bf16 h[4]; short4 s; } u;
    float vv[4] = {v.x, v.y, v.z, v.w};
    #pragma unroll
    for (int k = 0; k < 4; k++) {
        int c = c4 + k;
        float mu = sum[c] * invn;
        float var = sumsq[c] * invn - mu * mu;
        float r = (vv[k] - mu) * rsqrtf(var + 1e-5f) * g[c] + b[c];
        u.h[k] = __float2bfloat16(r > 0.f ? r : 0.f);
    }
    ((short4*)out)[t] = u.s;
}

// ---------------- launch ----------------

extern "C" void kernel_launch(void* const* d_in, const int* in_sizes, int n_in,
                              void* d_out, int out_size, void* d_ws, size_t ws_size,
                              hipStream_t stream) {
    (void)n_in; (void)out_size; (void)ws_size;
    const int N = in_sizes[0] / 128;
    const int E = in_sizes[1];

    const int* src = (const int*)d_in[1];
    const int* dst = (const int*)d_in[2];
    float* out = (float*)d_out;

    char* p = (char*)d_ws;
    auto carve = [&](size_t bytes) {
        void* q = (void*)p;
        p += (bytes + 255) & ~(size_t)255;
        return q;
    };
    int*   mode    = (int*)  carve(256);
    bf16*  h_bf    = (bf16*) carve((size_t)N * 128 * 2);
    bf16*  zh      = (bf16*) carve((size_t)N * 160 * 2);
    float* lin     = (float*)carve((size_t)N * 160 * 4);
    float* el      = (float*)carve((size_t)N * 4 * 4);
    float* er      = (float*)carve((size_t)N * 4 * 4);
    float* bn0     = (float*)carve(256 * 4);
    float* bn1     = (float*)carve(256 * 4);
    int*   counts  = (int*)  carve((size_t)N * 4);
    int*   row_ptr = (int*)  carve((size_t)(N + 1) * 4);
    int*   cursor  = (int*)  carve((size_t)N * 4);
    int*   ssrc    = (int*)  carve((size_t)E * 4);
    bf16*  Wt0     = (bf16*) carve((size_t)2 * 128 * 128 * 2);
    bf16*  Wt1     = (bf16*) carve((size_t)2 * 128 * 128 * 2);
    bf16*  Wt2     = (bf16*) carve((size_t)2 * 160 * 128 * 2);
    float* W32[23];
    for (int i = 3; i < 23; i++) W32[i] = (float*)carve((size_t)in_sizes[i] * 4);

    // staging (no feat staging: layer-0 GEMM reads feat directly, mode-branched)
    k_probe<<<1, 64, 0, stream>>>(d_in[0], mode);
    StageArgs sa;
    for (int i = 3; i < 23; i++) sa.d[i - 3] = StageDesc{d_in[i], W32[i], in_sizes[i]};
    k_stage_all<<<dim3(20, 8), 256, 0, stream>>>(sa, mode);

    const float* Wc[3]  = {W32[3],  W32[8],  W32[13]};
    const float* alw[3] = {W32[4],  W32[9],  W32[14]};
    const float* arw[3] = {W32[5],  W32[10], W32[15]};
    const float* bcw[3] = {W32[6],  W32[11], W32[16]};
    const float* Wl[3]  = {W32[7],  W32[12], W32[17]};
    const float* g0 = W32[18];
    const float* b0 = W32[19];
    const float* g1 = W32[20];
    const float* b1 = W32[21];
    const float* bias_last = W32[22];

    k_wt_all<<<(106496 + 255) / 256, 256, 0, stream>>>(Wc[0], Wl[0], Wc[1], Wl[1], Wc[2], Wl[2],
                                                       Wt0, Wt1, Wt2);

    const int EB = (E + 255) / 256;
    const int GB_ROWS = (N + 63) / 64;
    const int NODE_BLK = (N + 3) / 4;

    // CSR by dst (shared across layers) + bn buffer zeroing
    k_zero_all<<<(N + 255) / 256, 256, 0, stream>>>(counts, bn0, bn1, N);
    k_hist<<<EB, 256, 0, stream>>>(dst, counts, E);
    k_scan<<<1, 1024, 0, stream>>>(counts, row_ptr, cursor, N);
    k_scatter<<<EB, 256, 0, stream>>>(src, dst, cursor, ssrc, E);

    // ---- layer 0 (HC=128): GEMM reads feat directly, fused el/er ----
    k_gemm_mfma<128, 16, true, true><<<dim3(GB_ROWS, 1), 256, 0, stream>>>(
        d_in[0], mode, Wt0, zh, lin, alw[0], arw[0], el, er, N);
    k_gather<128, 32, false><<<NODE_BLK, 256, 0, stream>>>(row_ptr, ssrc, el, er, bcw[0], zh,
                                                           lin, nullptr, nullptr, N);
    k_bn_stats<<<128, 256, 0, stream>>>(lin, bn0, bn0 + 128, N);
    k_bn_apply<<<(N * 32 + 255) / 256, 256, 0, stream>>>(lin, bn0, bn0 + 128, g0, b0, h_bf, N);

    // ---- layer 1 (HC=128): A = h_bf (bf16), fused el/er ----
    k_gemm_mfma<128, 16, false, true><<<dim3(GB_ROWS, 1), 256, 0, stream>>>(
        h_bf, mode, Wt1, zh, lin, alw[1], arw[1], el, er, N);
    k_gather<128, 32, false><<<NODE_BLK, 256, 0, stream>>>(row_ptr, ssrc, el, er, bcw[1], zh,
                                                           lin, nullptr, nullptr, N);
    k_bn_stats<<<128, 256, 0, stream>>>(lin, bn1, bn1 + 128, N);
    k_bn_apply<<<(N * 32 + 255) / 256, 256, 0, stream>>>(lin, bn1, bn1 + 128, g1, b1, h_bf, N);

    // ---- layer 2 (HC=160, D=40): CT=10, y=2; separate elr; gather with fused out ----
    k_gemm_mfma<160, 10, false, false><<<dim3(GB_ROWS, 2), 256, 0, stream>>>(
        h_bf, mode, Wt2, zh, lin, nullptr, nullptr, nullptr, nullptr, N);
    k_elr<160, 40><<<(N * 4 + 255) / 256, 256, 0, stream>>>(zh, alw[2], arw[2], el, er, N);
    k_gather<160, 40, true><<<NODE_BLK, 256, 0, stream>>>(row_ptr, ssrc, el, er, bcw[2], zh,
                                                          lin, bias_last, out, N);
}